// Round 1
// baseline (385.925 us; speedup 1.0000x reference)
//
#include <hip/hip_runtime.h>
#include <cstdint>
#include <cstddef>

typedef unsigned short u16;
typedef unsigned int   u32;
typedef __attribute__((ext_vector_type(8))) short bf16x8;
typedef __attribute__((ext_vector_type(4))) float f32x4;

#define MFMA16(a,b,c) __builtin_amdgcn_mfma_f32_16x16x32_bf16((a),(b),(c),0,0,0)

__device__ __forceinline__ float bf2f(u16 h){
  union { u32 u; float f; } v; v.u = ((u32)h) << 16; return v.f;
}
__device__ __forceinline__ u16 f2bf(float f){
  union { float f; u32 u; } v; v.f = f;
  u32 u = v.u + 0x7FFFu + ((v.u >> 16) & 1u);
  return (u16)(u >> 16);
}
// dual-dtype scalar read: flag!=0 -> source is f32, else packed bf16
__device__ __forceinline__ float ldf(const void* p, int i, u32 isf32){
  return isf32 ? ((const float*)p)[i] : bf2f(((const u16*)p)[i]);
}

// ---------------------------------------------------------------------------
// kD: dtype probe. Read first 64 u16 of `inputs` as bf16; true bf16 N(0,1)
// stays |v|<10, f32-mantissa halves blow past 1e6 w.p. ~1-1e-8.
// ---------------------------------------------------------------------------
__global__ void kD_detect(const u16* __restrict__ raw, u32* __restrict__ flag)
{
  const int lane = threadIdx.x & 63;
  const float v = bf2f(raw[lane]);
  const unsigned long long big = __ballot(fabsf(v) > 1.0e6f);
  if (lane == 0) flag[0] = (big != 0ull) ? 1u : 0u;
}

// ---------------------------------------------------------------------------
// kC: canonicalize a tensor to bf16 (convert from f32, or bit-copy bf16).
// n multiple of 8.
// ---------------------------------------------------------------------------
__global__ void kC_conv(const void* __restrict__ src, u16* __restrict__ dst,
                        int n, const u32* __restrict__ flag)
{
  const int i8 = (blockIdx.x * 256 + threadIdx.x) << 3;
  if (i8 >= n) return;
  if (flag[0]) {
    const float4 a = ((const float4*)src)[i8 >> 2];
    const float4 b = ((const float4*)src)[(i8 >> 2) + 1];
    u16 o[8] = { f2bf(a.x), f2bf(a.y), f2bf(a.z), f2bf(a.w),
                 f2bf(b.x), f2bf(b.y), f2bf(b.z), f2bf(b.w) };
    *(uint4*)&dst[i8] = *(const uint4*)o;
  } else {
    ((uint4*)dst)[i8 >> 3] = ((const uint4*)src)[i8 >> 3];
  }
}

// ---------------------------------------------------------------------------
// kP: param block PB (u16), dual-path reads:
// [0,16384) dgf_opW | [16384,32768) gat_opW | [32768,33024) dgf_b
// [33024,33280) dgf_opb | [33280,33536) gat_opb | [33536,33792) ln_g
// [33792,34048) ln_b
// ---------------------------------------------------------------------------
__global__ void kP_params(const void* dgf_opW, const void* gat_opW,
                          const void* dgf_b,   const void* dgf_opb,
                          const void* gat_opb, const void* ln_g,
                          const void* ln_b,    u16* __restrict__ PB,
                          const u32* __restrict__ flag)
{
  const int i = blockIdx.x * 256 + threadIdx.x;
  if (i >= 34048) return;
  const u32 f = flag[0];
  float v;
  if      (i < 16384) v = ldf(dgf_opW, i, f);
  else if (i < 32768) v = ldf(gat_opW, i - 16384, f);
  else if (i < 33024) v = ldf(dgf_b,   i - 32768, f);
  else if (i < 33280) v = ldf(dgf_opb, i - 33024, f);
  else if (i < 33536) v = ldf(gat_opb, i - 33280, f);
  else if (i < 33792) v = ldf(ln_g,    i - 33536, f);
  else                v = ldf(ln_b,    i - 33792, f);
  PB[i] = f2bf(v);
}

// ---------------------------------------------------------------------------
// K0: WcatT [1024,256] bf16, dual-path reads:
//   rows   0-255 : dgf_W[i][o] (transpose)   rows 256-511 : Wk[o][i]
//   rows 512-767 : Wv[o][i]                  rows 768-1023: Wq[o][i]*a_w[o]/16
// ---------------------------------------------------------------------------
__global__ void k0_wcat(const void* dgfW, const void* Wk, const void* Wv,
                        const void* Wq, const void* aw, u16* __restrict__ Wcat,
                        const u32* __restrict__ flag)
{
  const int o = blockIdx.x;
  const int i = threadIdx.x;
  const u32 f = flag[0];
  float v;
  if (o < 256)       v = ldf(dgfW, i * 256 + o, f);
  else if (o < 512)  v = ldf(Wk, (o - 256) * 256 + i, f);
  else if (o < 768)  v = ldf(Wv, (o - 512) * 256 + i, f);
  else               v = ldf(Wq, (o - 768) * 256 + i, f) * ldf(aw, o - 768, f) * 0.0625f;
  Wcat[o * 256 + i] = f2bf(v);
}

// ---------------------------------------------------------------------------
// K1: X[32768,256] @ WcatT^T, 128x128 tiles, BK=64, XOR-swizzled LDS.
// ct 0-3: support/Whk -> P ; 6,7: Whq_pre -> P
// ct 4,5: Whv -> T rows 256-511 (swapped => C^T) ; 8,9: support -> T rows 0-255
// P [32768,768]: 0-255 support, 256-511 Whk, 512-767 Whq_pre.
// T [64][512][512]: rows 0-255 supportT, 256-511 WhvT.
// ---------------------------------------------------------------------------
__global__ __launch_bounds__(256, 2)
void k1_proj(const u16* __restrict__ X, const u16* __restrict__ W,
             u16* __restrict__ P, u16* __restrict__ T)
{
  __shared__ __align__(16) u16 ldsA[128 * 64];
  __shared__ __align__(16) u16 ldsB[128 * 64];
  const int bt = blockIdx.x;
  const int ct = blockIdx.y;
  const int r0 = bt << 7;
  const bool swapped = (ct == 4) | (ct == 5) | (ct >= 8);
  const int wbase = (ct < 8) ? (ct << 7) : ((ct - 8) << 7);
  const int tid = threadIdx.x;
  const int wave = tid >> 6;
  const int lane = tid & 63;
  const int wm = wave >> 1, wn = wave & 1;

  f32x4 acc[4][4];
#pragma unroll
  for (int i = 0; i < 4; ++i)
#pragma unroll
    for (int j = 0; j < 4; ++j) acc[i][j] = f32x4{0.f, 0.f, 0.f, 0.f};

  for (int kt = 0; kt < 4; ++kt) {
    __syncthreads();
#pragma unroll
    for (int s = 0; s < 4; ++s) {
      const int slot = ((wave * 4 + s) << 6) + lane;
      const int m = slot >> 3, c = slot & 7;
      const int kb = c ^ (m & 7);
      *(uint4*)&ldsA[slot << 3] =
          *(const uint4*)(X + (r0 + m) * 256 + (kt << 6) + (kb << 3));
      *(uint4*)&ldsB[slot << 3] =
          *(const uint4*)(W + (wbase + m) * 256 + (kt << 6) + (kb << 3));
    }
    __syncthreads();
#pragma unroll
    for (int ks = 0; ks < 2; ++ks) {
      const int kb = (ks << 2) + (lane >> 4);
      bf16x8 fa[4], fb[4];
#pragma unroll
      for (int i = 0; i < 4; ++i) {
        const int m = (wm << 6) + (i << 4) + (lane & 15);
        fa[i] = *(const bf16x8*)&ldsA[((m << 3) + (kb ^ (m & 7))) << 3];
        const int n = (wn << 6) + (i << 4) + (lane & 15);
        fb[i] = *(const bf16x8*)&ldsB[((n << 3) + (kb ^ (n & 7))) << 3];
      }
      if (!swapped) {
#pragma unroll
        for (int i = 0; i < 4; ++i)
#pragma unroll
          for (int j = 0; j < 4; ++j)
            acc[i][j] = MFMA16(fa[i], fb[j], acc[i][j]);
      } else {
#pragma unroll
        for (int i = 0; i < 4; ++i)
#pragma unroll
          for (int j = 0; j < 4; ++j)
            acc[i][j] = MFMA16(fb[i], fa[j], acc[i][j]);
      }
    }
  }

  if (!swapped) {
    const int pcb = (ct < 4) ? (ct << 7) : ((ct - 2) << 7);
#pragma unroll
    for (int i = 0; i < 4; ++i) {
      const int row = r0 + (wm << 6) + (i << 4) + ((lane >> 4) << 2);
#pragma unroll
      for (int j = 0; j < 4; ++j) {
        const int col = pcb + (wn << 6) + (j << 4) + (lane & 15);
#pragma unroll
        for (int r = 0; r < 4; ++r)
          P[(row + r) * 768 + col] = f2bf(acc[i][j][r]);
      }
    }
  } else {
    // acc[i][j] = MFMA(fb[i], fa[j]): C rows carry wn offset, C cols carry wm.
    const int trb = (wbase >= 512) ? (wbase - 256) : wbase;
    const int b = r0 >> 9;
    const int e0 = r0 & 511;
    u16* Tb = T + ((size_t)b << 18);
#pragma unroll
    for (int i = 0; i < 4; ++i) {
      const int trow = trb + (wn << 6) + (i << 4) + ((lane >> 4) << 2);
#pragma unroll
      for (int j = 0; j < 4; ++j) {
        const int e = e0 + (wm << 6) + (j << 4) + (lane & 15);
#pragma unroll
        for (int r = 0; r < 4; ++r)
          Tb[((trow + r) << 9) + e] = f2bf(acc[i][j][r]);
      }
    }
  }
}

// ---------------------------------------------------------------------------
// K2: gates = sigmoid(op_emb[32768,64] @ opW^T + b) -> G[32768,512] bf16
// cols 0-255 gate_d, 256-511 gate_g. Weights/biases from PB.
// ---------------------------------------------------------------------------
__global__ __launch_bounds__(256, 2)
void k2_gates(const u16* __restrict__ OP, const u16* __restrict__ PB,
              u16* __restrict__ G)
{
  __shared__ __align__(16) u16 ldsA[128 * 64];
  __shared__ __align__(16) u16 ldsB[128 * 64];
  const int bt = blockIdx.x, ct = blockIdx.y;
  const int r0 = bt << 7;
  const u16* Wp = (ct < 2) ? (PB + (ct << 7) * 64) : (PB + 16384 + ((ct - 2) << 7) * 64);
  const u16* Bp = (ct < 2) ? (PB + 33024 + (ct << 7)) : (PB + 33280 + ((ct - 2) << 7));
  const int tid = threadIdx.x, wave = tid >> 6, lane = tid & 63;
  const int wm = wave >> 1, wn = wave & 1;

  f32x4 acc[4][4];
#pragma unroll
  for (int i = 0; i < 4; ++i)
#pragma unroll
    for (int j = 0; j < 4; ++j) acc[i][j] = f32x4{0.f, 0.f, 0.f, 0.f};

#pragma unroll
  for (int s = 0; s < 4; ++s) {
    const int slot = ((wave * 4 + s) << 6) + lane;
    const int m = slot >> 3, c = slot & 7;
    const int kb = c ^ (m & 7);
    *(uint4*)&ldsA[slot << 3] = *(const uint4*)(OP + (r0 + m) * 64 + (kb << 3));
    *(uint4*)&ldsB[slot << 3] = *(const uint4*)(Wp + m * 64 + (kb << 3));
  }
  __syncthreads();
#pragma unroll
  for (int ks = 0; ks < 2; ++ks) {
    const int kb = (ks << 2) + (lane >> 4);
    bf16x8 fa[4], fb[4];
#pragma unroll
    for (int i = 0; i < 4; ++i) {
      const int m = (wm << 6) + (i << 4) + (lane & 15);
      fa[i] = *(const bf16x8*)&ldsA[((m << 3) + (kb ^ (m & 7))) << 3];
      const int n = (wn << 6) + (i << 4) + (lane & 15);
      fb[i] = *(const bf16x8*)&ldsB[((n << 3) + (kb ^ (n & 7))) << 3];
    }
#pragma unroll
    for (int i = 0; i < 4; ++i)
#pragma unroll
      for (int j = 0; j < 4; ++j)
        acc[i][j] = MFMA16(fa[i], fb[j], acc[i][j]);
  }
#pragma unroll
  for (int i = 0; i < 4; ++i) {
    const int row = r0 + (wm << 6) + (i << 4) + ((lane >> 4) << 2);
#pragma unroll
    for (int j = 0; j < 4; ++j) {
      const int cw = (wn << 6) + (j << 4) + (lane & 15);
      const float bias = bf2f(Bp[cw]);
      const int col = (ct << 7) + cw;
#pragma unroll
      for (int r = 0; r < 4; ++r) {
        const float x = acc[i][j][r] + bias;
        G[((row + r) << 9) + col] = f2bf(1.0f / (1.0f + __expf(-x)));
      }
    }
  }
}

// ---------------------------------------------------------------------------
// K3: per-batch scores S = Whq_pre @ Whk^T; E = exp(leaky(S)*adj) bf16.
// No max-subtraction: |alpha| < ~0.2 by construction.
// ---------------------------------------------------------------------------
__global__ __launch_bounds__(256, 2)
void k3_scores(const u16* __restrict__ P, const u16* __restrict__ adj,
               u16* __restrict__ E)
{
  __shared__ __align__(16) u16 ldsA[128 * 64];
  __shared__ __align__(16) u16 ldsB[128 * 64];
  const int lt = blockIdx.x, et = blockIdx.y, b = blockIdx.z;
  const int e0 = et << 7, l0 = lt << 7;
  const int tid = threadIdx.x, wave = tid >> 6, lane = tid & 63;
  const int wm = wave >> 1, wn = wave & 1;
  const int rowQ = (b << 9) + e0;
  const int rowK = (b << 9) + l0;

  f32x4 acc[4][4];
#pragma unroll
  for (int i = 0; i < 4; ++i)
#pragma unroll
    for (int j = 0; j < 4; ++j) acc[i][j] = f32x4{0.f, 0.f, 0.f, 0.f};

  for (int kt = 0; kt < 4; ++kt) {
    __syncthreads();
#pragma unroll
    for (int s = 0; s < 4; ++s) {
      const int slot = ((wave * 4 + s) << 6) + lane;
      const int m = slot >> 3, c = slot & 7;
      const int kb = c ^ (m & 7);
      *(uint4*)&ldsA[slot << 3] =
          *(const uint4*)(P + (rowQ + m) * 768 + 512 + (kt << 6) + (kb << 3));
      *(uint4*)&ldsB[slot << 3] =
          *(const uint4*)(P + (rowK + m) * 768 + 256 + (kt << 6) + (kb << 3));
    }
    __syncthreads();
#pragma unroll
    for (int ks = 0; ks < 2; ++ks) {
      const int kb = (ks << 2) + (lane >> 4);
      bf16x8 fa[4], fb[4];
#pragma unroll
      for (int i = 0; i < 4; ++i) {
        const int m = (wm << 6) + (i << 4) + (lane & 15);
        fa[i] = *(const bf16x8*)&ldsA[((m << 3) + (kb ^ (m & 7))) << 3];
        const int n = (wn << 6) + (i << 4) + (lane & 15);
        fb[i] = *(const bf16x8*)&ldsB[((n << 3) + (kb ^ (n & 7))) << 3];
      }
#pragma unroll
      for (int i = 0; i < 4; ++i)
#pragma unroll
        for (int j = 0; j < 4; ++j)
          acc[i][j] = MFMA16(fa[i], fb[j], acc[i][j]);
    }
  }
#pragma unroll
  for (int i = 0; i < 4; ++i) {
    const int e = e0 + (wm << 6) + (i << 4) + ((lane >> 4) << 2);
#pragma unroll
    for (int j = 0; j < 4; ++j) {
      const int l = l0 + (wn << 6) + (j << 4) + (lane & 15);
#pragma unroll
      for (int r = 0; r < 4; ++r) {
        const int idx = (((b << 9) + e + r) << 9) + l;
        const float a = bf2f(adj[idx]);
        float s = acc[i][j][r];
        s = (s > 0.0f ? s : 0.2f * s) * a;
        E[idx] = f2bf(__expf(s));
      }
    }
  }
}

// ---------------------------------------------------------------------------
// K4: per (b, 32-row e-tile), LDS-free streaming GEMM pair:
//   phase0: H = E @ Whv (WhvT rows of T)   phase1: D = adj @ support (SupT)
//   rowsum(E) fused as an extra MFMA against a constant all-ones B fragment
//   (replaces the old k3b kernel).
// All operands have the contraction dim (l) contiguous -> A/B MFMA fragments
// load directly from global as bf16x8; the 16 k-step offsets fold into load
// immediates. No barriers in the main loop; latency hidden by 12-deep load
// ILP x ~12 waves/CU.
// epilogue: h' = gate_g*H/rowsum ; LayerNorm ; dense = gate_d*D + sup + dgf_b;
//           out = 0.5*(dense+gat). Output dtype per flag.
// ---------------------------------------------------------------------------
__global__ __launch_bounds__(256, 3)
void k4_out(const u16* __restrict__ P, const u16* __restrict__ T,
            const u16* __restrict__ E, const u16* __restrict__ adj,
            const u16* __restrict__ G, const u16* __restrict__ PB,
            void* __restrict__ out, const u32* __restrict__ flag)
{
  __shared__ float red[32][8];
  const int et = blockIdx.x, b = blockIdx.y;
  const int e0 = et << 5;
  const int tid = threadIdx.x;
  const int wn = tid >> 6;          // wave owns output cols [wn*64, wn*64+64)
  const int lane = tid & 63;
  const int lr = lane & 15;         // fragment lane row/col
  const int kc = (lane >> 4) << 3;  // k-chunk element offset within 32
  const size_t abase = ((size_t)((b << 9) + e0)) << 9;

  // per-thread fragment base pointers (contraction dim contiguous)
  const u16* pE[2]; const u16* pA[2]; const u16* pBv[4]; const u16* pBs[4];
#pragma unroll
  for (int i = 0; i < 2; ++i) {
    const size_t ro = abase + ((size_t)((i << 4) + lr) << 9) + kc;
    pE[i] = E + ro;
    pA[i] = adj + ro;
  }
  const u16* Tb = T + ((size_t)b << 18);
#pragma unroll
  for (int j = 0; j < 4; ++j) {
    const int n = (wn << 6) + (j << 4) + lr;
    pBv[j] = Tb + ((size_t)(256 + n) << 9) + kc;   // WhvT rows 256-511
    pBs[j] = Tb + ((size_t)n << 9) + kc;           // supportT rows 0-255
  }

  f32x4 acc0[2][4], acc1[2][4], accS[2];
#pragma unroll
  for (int i = 0; i < 2; ++i) {
    accS[i] = f32x4{0.f, 0.f, 0.f, 0.f};
#pragma unroll
    for (int j = 0; j < 4; ++j) {
      acc0[i][j] = f32x4{0.f, 0.f, 0.f, 0.f};
      acc1[i][j] = f32x4{0.f, 0.f, 0.f, 0.f};
    }
  }
  const short onebf = (short)0x3F80;  // bf16 1.0
  const bf16x8 ones = {onebf, onebf, onebf, onebf, onebf, onebf, onebf, onebf};

  for (int ks = 0; ks < 16; ++ks) {
    const int off = ks << 5;
    bf16x8 fae[2], faa[2], fbv[4], fbs[4];
#pragma unroll
    for (int i = 0; i < 2; ++i) {
      fae[i] = *(const bf16x8*)(pE[i] + off);
      faa[i] = *(const bf16x8*)(pA[i] + off);
    }
#pragma unroll
    for (int j = 0; j < 4; ++j) {
      fbv[j] = *(const bf16x8*)(pBv[j] + off);
      fbs[j] = *(const bf16x8*)(pBs[j] + off);
    }
#pragma unroll
    for (int i = 0; i < 2; ++i) {
#pragma unroll
      for (int j = 0; j < 4; ++j) {
        acc0[i][j] = MFMA16(fae[i], fbv[j], acc0[i][j]);
        acc1[i][j] = MFMA16(faa[i], fbs[j], acc1[i][j]);
      }
      accS[i] = MFMA16(fae[i], ones, accS[i]);  // rowsum(E) slice
    }
  }

  const u16* dgf_b = PB + 32768;
  const u16* ln_g  = PB + 33536;
  const u16* ln_b  = PB + 33792;
  const u32 isf32 = flag[0];

  float lng[4], lnb[4], dgb[4];
#pragma unroll
  for (int j = 0; j < 4; ++j) {
    const int col = (wn << 6) + (j << 4) + lr;
    lng[j] = bf2f(ln_g[col]);
    lnb[j] = bf2f(ln_b[col]);
    dgb[j] = bf2f(dgf_b[col]);
  }

  // phase-0 normalize (gate_g * H / rowsum) + per-wave LN partial sums
#pragma unroll
  for (int i = 0; i < 2; ++i) {
#pragma unroll
    for (int r = 0; r < 4; ++r) {
      const int rl = (i << 4) + ((lane >> 4) << 2) + r;
      const int grow = (b << 9) + e0 + rl;
      const float invS = 1.0f / accS[i][r];
      float ps = 0.0f, pq = 0.0f;
#pragma unroll
      for (int j = 0; j < 4; ++j) {
        const int col = (wn << 6) + (j << 4) + lr;
        const float gg = bf2f(G[((size_t)grow << 9) + 256 + col]);
        const float hp = gg * acc0[i][j][r] * invS;
        acc0[i][j][r] = hp;
        ps += hp; pq += hp * hp;
      }
#pragma unroll
      for (int m = 1; m < 16; m <<= 1) {
        ps += __shfl_xor(ps, m, 64);
        pq += __shfl_xor(pq, m, 64);
      }
      if (lr == 0) { red[rl][wn << 1] = ps; red[rl][(wn << 1) + 1] = pq; }
    }
  }
  __syncthreads();
#pragma unroll
  for (int i = 0; i < 2; ++i) {
#pragma unroll
    for (int r = 0; r < 4; ++r) {
      const int rl = (i << 4) + ((lane >> 4) << 2) + r;
      const int grow = (b << 9) + e0 + rl;
      const float mean = (red[rl][0] + red[rl][2] + red[rl][4] + red[rl][6]) * (1.0f / 256.0f);
      const float ex2  = (red[rl][1] + red[rl][3] + red[rl][5] + red[rl][7]) * (1.0f / 256.0f);
      const float rstd = rsqrtf(ex2 - mean * mean + 1e-5f);
#pragma unroll
      for (int j = 0; j < 4; ++j) {
        const int col = (wn << 6) + (j << 4) + lr;
        const float gat = (acc0[i][j][r] - mean) * rstd * lng[j] + lnb[j];
        const float gd = bf2f(G[((size_t)grow << 9) + col]);
        const float sup = bf2f(P[grow * 768 + col]);
        const float dense = gd * acc1[i][j][r] + sup + dgb[j];
        const float o = 0.5f * (dense + gat);
        if (isf32) ((float*)out)[grow * 256 + col] = o;
        else       ((u16*)out)[grow * 256 + col] = f2bf(o);
      }
    }
  }
}

// ---------------------------------------------------------------------------
extern "C" void kernel_launch(void* const* d_in, const int* in_sizes, int n_in,
                              void* d_out, int out_size, void* d_ws, size_t ws_size,
                              hipStream_t stream)
{
  (void)in_sizes; (void)n_in; (void)out_size; (void)ws_size;
  const void* inputs  = d_in[0];
  const void* adj     = d_in[1];
  const void* op_emb  = d_in[2];
  const void* dgf_W   = d_in[3];
  const void* dgf_b   = d_in[4];
  const void* dgf_opW = d_in[5];
  const void* dgf_opb = d_in[6];
  const void* Wk      = d_in[7];
  const void* Wv      = d_in[8];
  const void* Wq      = d_in[9];
  const void* a_w     = d_in[10];
  const void* gat_opW = d_in[11];
  const void* gat_opb = d_in[12];
  const void* ln_g    = d_in[13];
  const void* ln_b    = d_in[14];
  char* ws = (char*)d_ws;

  // workspace layout (bytes)
  u16*  P    = (u16*)(ws);                    // [32768,768]  50331648
  u16*  T    = (u16*)(ws + 50331648ull);      // [64,512,512] 33554432
  u16*  E    = (u16*)(ws + 83886080ull);      // [64,512,512] 33554432
  u16*  G    = (u16*)(ws + 117440512ull);     // [32768,512]  33554432
  u16*  Cadj = (u16*)(ws + 150994944ull);     // [64,512,512] 33554432
  u16*  Cin  = (u16*)(ws + 184549376ull);     // [32768,256]  16777216
  u16*  Cop  = (u16*)(ws + 201326592ull);     // [32768,64]    4194304
  u16*  Wcat = (u16*)(ws + 205520896ull);     // [1024,256]     524288
  u16*  PB   = (u16*)(ws + 206045184ull);     // params          69632
  u32*  flag = (u32*)(ws + 206245888ull);     // dtype flag        256

  kD_detect <<<dim3(1),       dim3(64),  0, stream>>>((const u16*)inputs, flag);
  kC_conv   <<<dim3(4096),    dim3(256), 0, stream>>>(inputs, Cin,  8388608, flag);
  kC_conv   <<<dim3(1024),    dim3(256), 0, stream>>>(op_emb, Cop,  2097152, flag);
  kC_conv   <<<dim3(8192),    dim3(256), 0, stream>>>(adj,    Cadj, 16777216, flag);
  kP_params <<<dim3(134),     dim3(256), 0, stream>>>(dgf_opW, gat_opW, dgf_b,
                                                      dgf_opb, gat_opb, ln_g, ln_b,
                                                      PB, flag);
  k0_wcat   <<<dim3(1024),    dim3(256), 0, stream>>>(dgf_W, Wk, Wv, Wq, a_w,
                                                      Wcat, flag);
  k1_proj   <<<dim3(256, 10), dim3(256), 0, stream>>>(Cin, Wcat, P, T);
  k2_gates  <<<dim3(256, 4),  dim3(256), 0, stream>>>(Cop, PB, G);
  k3_scores <<<dim3(4, 4, 64),dim3(256), 0, stream>>>(P, Cadj, E);
  k4_out    <<<dim3(16, 64),  dim3(256), 0, stream>>>(P, T, E, Cadj, G,
                                                      PB, d_out, flag);
}

// Round 2
// 337.488 us; speedup vs baseline: 1.1435x; 1.1435x over previous
//
#include <hip/hip_runtime.h>
#include <cstdint>
#include <cstddef>

typedef unsigned short u16;
typedef unsigned int   u32;
typedef __attribute__((ext_vector_type(8))) short bf16x8;
typedef __attribute__((ext_vector_type(4))) float f32x4;

#define MFMA16(a,b,c) __builtin_amdgcn_mfma_f32_16x16x32_bf16((a),(b),(c),0,0,0)

__device__ __forceinline__ float bf2f(u16 h){
  union { u32 u; float f; } v; v.u = ((u32)h) << 16; return v.f;
}
__device__ __forceinline__ u16 f2bf(float f){
  union { float f; u32 u; } v; v.f = f;
  u32 u = v.u + 0x7FFFu + ((v.u >> 16) & 1u);
  return (u16)(u >> 16);
}
// dual-dtype scalar read: flag!=0 -> source is f32, else packed bf16
__device__ __forceinline__ float ldf(const void* p, int i, u32 isf32){
  return isf32 ? ((const float*)p)[i] : bf2f(((const u16*)p)[i]);
}
// async global->LDS DMA, 16B per lane. LDS dest: wave-uniform base + lane*16.
__device__ __forceinline__ void gld16(const u16* g, u16* l){
  __builtin_amdgcn_global_load_lds(
      (const __attribute__((address_space(1))) void*)g,
      (__attribute__((address_space(3))) void*)l, 16, 0, 0);
}

// ---------------------------------------------------------------------------
// kD: dtype probe. Read first 64 u16 of `inputs` as bf16; true bf16 N(0,1)
// stays |v|<10, f32-mantissa halves blow past 1e6 w.p. ~1-1e-8.
// ---------------------------------------------------------------------------
__global__ void kD_detect(const u16* __restrict__ raw, u32* __restrict__ flag)
{
  const int lane = threadIdx.x & 63;
  const float v = bf2f(raw[lane]);
  const unsigned long long big = __ballot(fabsf(v) > 1.0e6f);
  if (lane == 0) flag[0] = (big != 0ull) ? 1u : 0u;
}

// ---------------------------------------------------------------------------
// kC: canonicalize a tensor to bf16 (convert from f32, or bit-copy bf16).
// n multiple of 8.
// ---------------------------------------------------------------------------
__global__ void kC_conv(const void* __restrict__ src, u16* __restrict__ dst,
                        int n, const u32* __restrict__ flag)
{
  const int i8 = (blockIdx.x * 256 + threadIdx.x) << 3;
  if (i8 >= n) return;
  if (flag[0]) {
    const float4 a = ((const float4*)src)[i8 >> 2];
    const float4 b = ((const float4*)src)[(i8 >> 2) + 1];
    u16 o[8] = { f2bf(a.x), f2bf(a.y), f2bf(a.z), f2bf(a.w),
                 f2bf(b.x), f2bf(b.y), f2bf(b.z), f2bf(b.w) };
    *(uint4*)&dst[i8] = *(const uint4*)o;
  } else {
    ((uint4*)dst)[i8 >> 3] = ((const uint4*)src)[i8 >> 3];
  }
}

// ---------------------------------------------------------------------------
// kP: param block PB (u16), dual-path reads:
// [0,16384) dgf_opW | [16384,32768) gat_opW | [32768,33024) dgf_b
// [33024,33280) dgf_opb | [33280,33536) gat_opb | [33536,33792) ln_g
// [33792,34048) ln_b
// ---------------------------------------------------------------------------
__global__ void kP_params(const void* dgf_opW, const void* gat_opW,
                          const void* dgf_b,   const void* dgf_opb,
                          const void* gat_opb, const void* ln_g,
                          const void* ln_b,    u16* __restrict__ PB,
                          const u32* __restrict__ flag)
{
  const int i = blockIdx.x * 256 + threadIdx.x;
  if (i >= 34048) return;
  const u32 f = flag[0];
  float v;
  if      (i < 16384) v = ldf(dgf_opW, i, f);
  else if (i < 32768) v = ldf(gat_opW, i - 16384, f);
  else if (i < 33024) v = ldf(dgf_b,   i - 32768, f);
  else if (i < 33280) v = ldf(dgf_opb, i - 33024, f);
  else if (i < 33536) v = ldf(gat_opb, i - 33280, f);
  else if (i < 33792) v = ldf(ln_g,    i - 33536, f);
  else                v = ldf(ln_b,    i - 33792, f);
  PB[i] = f2bf(v);
}

// ---------------------------------------------------------------------------
// K0: WcatT [1024,256] bf16, dual-path reads:
//   rows   0-255 : dgf_W[i][o] (transpose)   rows 256-511 : Wk[o][i]
//   rows 512-767 : Wv[o][i]                  rows 768-1023: Wq[o][i]*a_w[o]/16
// ---------------------------------------------------------------------------
__global__ void k0_wcat(const void* dgfW, const void* Wk, const void* Wv,
                        const void* Wq, const void* aw, u16* __restrict__ Wcat,
                        const u32* __restrict__ flag)
{
  const int o = blockIdx.x;
  const int i = threadIdx.x;
  const u32 f = flag[0];
  float v;
  if (o < 256)       v = ldf(dgfW, i * 256 + o, f);
  else if (o < 512)  v = ldf(Wk, (o - 256) * 256 + i, f);
  else if (o < 768)  v = ldf(Wv, (o - 512) * 256 + i, f);
  else               v = ldf(Wq, (o - 768) * 256 + i, f) * ldf(aw, o - 768, f) * 0.0625f;
  Wcat[o * 256 + i] = f2bf(v);
}

// ---------------------------------------------------------------------------
// K1: X[32768,256] @ WcatT^T, 128x128 tiles, BK=64, XOR-swizzled LDS.
// ct 0-3: support/Whk -> P ; 6,7: Whq_pre -> P
// ct 4,5: Whv -> T rows 256-511 (swapped => C^T) ; 8,9: support -> T rows 0-255
// P [32768,768]: 0-255 support, 256-511 Whk, 512-767 Whq_pre.
// T [64][512][512]: rows 0-255 supportT, 256-511 WhvT.
// ---------------------------------------------------------------------------
__global__ __launch_bounds__(256, 2)
void k1_proj(const u16* __restrict__ X, const u16* __restrict__ W,
             u16* __restrict__ P, u16* __restrict__ T)
{
  __shared__ __align__(16) u16 ldsA[128 * 64];
  __shared__ __align__(16) u16 ldsB[128 * 64];
  const int bt = blockIdx.x;
  const int ct = blockIdx.y;
  const int r0 = bt << 7;
  const bool swapped = (ct == 4) | (ct == 5) | (ct >= 8);
  const int wbase = (ct < 8) ? (ct << 7) : ((ct - 8) << 7);
  const int tid = threadIdx.x;
  const int wave = tid >> 6;
  const int lane = tid & 63;
  const int wm = wave >> 1, wn = wave & 1;

  f32x4 acc[4][4];
#pragma unroll
  for (int i = 0; i < 4; ++i)
#pragma unroll
    for (int j = 0; j < 4; ++j) acc[i][j] = f32x4{0.f, 0.f, 0.f, 0.f};

  for (int kt = 0; kt < 4; ++kt) {
    __syncthreads();
#pragma unroll
    for (int s = 0; s < 4; ++s) {
      const int slot = ((wave * 4 + s) << 6) + lane;
      const int m = slot >> 3, c = slot & 7;
      const int kb = c ^ (m & 7);
      *(uint4*)&ldsA[slot << 3] =
          *(const uint4*)(X + (r0 + m) * 256 + (kt << 6) + (kb << 3));
      *(uint4*)&ldsB[slot << 3] =
          *(const uint4*)(W + (wbase + m) * 256 + (kt << 6) + (kb << 3));
    }
    __syncthreads();
#pragma unroll
    for (int ks = 0; ks < 2; ++ks) {
      const int kb = (ks << 2) + (lane >> 4);
      bf16x8 fa[4], fb[4];
#pragma unroll
      for (int i = 0; i < 4; ++i) {
        const int m = (wm << 6) + (i << 4) + (lane & 15);
        fa[i] = *(const bf16x8*)&ldsA[((m << 3) + (kb ^ (m & 7))) << 3];
        const int n = (wn << 6) + (i << 4) + (lane & 15);
        fb[i] = *(const bf16x8*)&ldsB[((n << 3) + (kb ^ (n & 7))) << 3];
      }
      if (!swapped) {
#pragma unroll
        for (int i = 0; i < 4; ++i)
#pragma unroll
          for (int j = 0; j < 4; ++j)
            acc[i][j] = MFMA16(fa[i], fb[j], acc[i][j]);
      } else {
#pragma unroll
        for (int i = 0; i < 4; ++i)
#pragma unroll
          for (int j = 0; j < 4; ++j)
            acc[i][j] = MFMA16(fb[i], fa[j], acc[i][j]);
      }
    }
  }

  if (!swapped) {
    const int pcb = (ct < 4) ? (ct << 7) : ((ct - 2) << 7);
#pragma unroll
    for (int i = 0; i < 4; ++i) {
      const int row = r0 + (wm << 6) + (i << 4) + ((lane >> 4) << 2);
#pragma unroll
      for (int j = 0; j < 4; ++j) {
        const int col = pcb + (wn << 6) + (j << 4) + (lane & 15);
#pragma unroll
        for (int r = 0; r < 4; ++r)
          P[(row + r) * 768 + col] = f2bf(acc[i][j][r]);
      }
    }
  } else {
    // acc[i][j] = MFMA(fb[i], fa[j]): C rows carry wn offset, C cols carry wm.
    const int trb = (wbase >= 512) ? (wbase - 256) : wbase;
    const int b = r0 >> 9;
    const int e0 = r0 & 511;
    u16* Tb = T + ((size_t)b << 18);
#pragma unroll
    for (int i = 0; i < 4; ++i) {
      const int trow = trb + (wn << 6) + (i << 4) + ((lane >> 4) << 2);
#pragma unroll
      for (int j = 0; j < 4; ++j) {
        const int e = e0 + (wm << 6) + (j << 4) + (lane & 15);
#pragma unroll
        for (int r = 0; r < 4; ++r)
          Tb[((trow + r) << 9) + e] = f2bf(acc[i][j][r]);
      }
    }
  }
}

// ---------------------------------------------------------------------------
// K2: gates = sigmoid(op_emb[32768,64] @ opW^T + b) -> G[32768,512] bf16
// cols 0-255 gate_d, 256-511 gate_g. Weights/biases from PB.
// ---------------------------------------------------------------------------
__global__ __launch_bounds__(256, 2)
void k2_gates(const u16* __restrict__ OP, const u16* __restrict__ PB,
              u16* __restrict__ G)
{
  __shared__ __align__(16) u16 ldsA[128 * 64];
  __shared__ __align__(16) u16 ldsB[128 * 64];
  const int bt = blockIdx.x, ct = blockIdx.y;
  const int r0 = bt << 7;
  const u16* Wp = (ct < 2) ? (PB + (ct << 7) * 64) : (PB + 16384 + ((ct - 2) << 7) * 64);
  const u16* Bp = (ct < 2) ? (PB + 33024 + (ct << 7)) : (PB + 33280 + ((ct - 2) << 7));
  const int tid = threadIdx.x, wave = tid >> 6, lane = tid & 63;
  const int wm = wave >> 1, wn = wave & 1;

  f32x4 acc[4][4];
#pragma unroll
  for (int i = 0; i < 4; ++i)
#pragma unroll
    for (int j = 0; j < 4; ++j) acc[i][j] = f32x4{0.f, 0.f, 0.f, 0.f};

#pragma unroll
  for (int s = 0; s < 4; ++s) {
    const int slot = ((wave * 4 + s) << 6) + lane;
    const int m = slot >> 3, c = slot & 7;
    const int kb = c ^ (m & 7);
    *(uint4*)&ldsA[slot << 3] = *(const uint4*)(OP + (r0 + m) * 64 + (kb << 3));
    *(uint4*)&ldsB[slot << 3] = *(const uint4*)(Wp + m * 64 + (kb << 3));
  }
  __syncthreads();
#pragma unroll
  for (int ks = 0; ks < 2; ++ks) {
    const int kb = (ks << 2) + (lane >> 4);
    bf16x8 fa[4], fb[4];
#pragma unroll
    for (int i = 0; i < 4; ++i) {
      const int m = (wm << 6) + (i << 4) + (lane & 15);
      fa[i] = *(const bf16x8*)&ldsA[((m << 3) + (kb ^ (m & 7))) << 3];
      const int n = (wn << 6) + (i << 4) + (lane & 15);
      fb[i] = *(const bf16x8*)&ldsB[((n << 3) + (kb ^ (n & 7))) << 3];
    }
#pragma unroll
    for (int i = 0; i < 4; ++i)
#pragma unroll
      for (int j = 0; j < 4; ++j)
        acc[i][j] = MFMA16(fa[i], fb[j], acc[i][j]);
  }
#pragma unroll
  for (int i = 0; i < 4; ++i) {
    const int row = r0 + (wm << 6) + (i << 4) + ((lane >> 4) << 2);
#pragma unroll
    for (int j = 0; j < 4; ++j) {
      const int cw = (wn << 6) + (j << 4) + (lane & 15);
      const float bias = bf2f(Bp[cw]);
      const int col = (ct << 7) + cw;
#pragma unroll
      for (int r = 0; r < 4; ++r) {
        const float x = acc[i][j][r] + bias;
        G[((row + r) << 9) + col] = f2bf(1.0f / (1.0f + __expf(-x)));
      }
    }
  }
}

// ---------------------------------------------------------------------------
// K3: per-batch scores S = Whq_pre @ Whk^T; E = exp(leaky(S)*adj) bf16.
// No max-subtraction: |alpha| < ~0.2 by construction.
// ---------------------------------------------------------------------------
__global__ __launch_bounds__(256, 2)
void k3_scores(const u16* __restrict__ P, const u16* __restrict__ adj,
               u16* __restrict__ E)
{
  __shared__ __align__(16) u16 ldsA[128 * 64];
  __shared__ __align__(16) u16 ldsB[128 * 64];
  const int lt = blockIdx.x, et = blockIdx.y, b = blockIdx.z;
  const int e0 = et << 7, l0 = lt << 7;
  const int tid = threadIdx.x, wave = tid >> 6, lane = tid & 63;
  const int wm = wave >> 1, wn = wave & 1;
  const int rowQ = (b << 9) + e0;
  const int rowK = (b << 9) + l0;

  f32x4 acc[4][4];
#pragma unroll
  for (int i = 0; i < 4; ++i)
#pragma unroll
    for (int j = 0; j < 4; ++j) acc[i][j] = f32x4{0.f, 0.f, 0.f, 0.f};

  for (int kt = 0; kt < 4; ++kt) {
    __syncthreads();
#pragma unroll
    for (int s = 0; s < 4; ++s) {
      const int slot = ((wave * 4 + s) << 6) + lane;
      const int m = slot >> 3, c = slot & 7;
      const int kb = c ^ (m & 7);
      *(uint4*)&ldsA[slot << 3] =
          *(const uint4*)(P + (rowQ + m) * 768 + 512 + (kt << 6) + (kb << 3));
      *(uint4*)&ldsB[slot << 3] =
          *(const uint4*)(P + (rowK + m) * 768 + 256 + (kt << 6) + (kb << 3));
    }
    __syncthreads();
#pragma unroll
    for (int ks = 0; ks < 2; ++ks) {
      const int kb = (ks << 2) + (lane >> 4);
      bf16x8 fa[4], fb[4];
#pragma unroll
      for (int i = 0; i < 4; ++i) {
        const int m = (wm << 6) + (i << 4) + (lane & 15);
        fa[i] = *(const bf16x8*)&ldsA[((m << 3) + (kb ^ (m & 7))) << 3];
        const int n = (wn << 6) + (i << 4) + (lane & 15);
        fb[i] = *(const bf16x8*)&ldsB[((n << 3) + (kb ^ (n & 7))) << 3];
      }
#pragma unroll
      for (int i = 0; i < 4; ++i)
#pragma unroll
        for (int j = 0; j < 4; ++j)
          acc[i][j] = MFMA16(fa[i], fb[j], acc[i][j]);
    }
  }
#pragma unroll
  for (int i = 0; i < 4; ++i) {
    const int e = e0 + (wm << 6) + (i << 4) + ((lane >> 4) << 2);
#pragma unroll
    for (int j = 0; j < 4; ++j) {
      const int l = l0 + (wn << 6) + (j << 4) + (lane & 15);
#pragma unroll
      for (int r = 0; r < 4; ++r) {
        const int idx = (((b << 9) + e + r) << 9) + l;
        const float a = bf2f(adj[idx]);
        float s = acc[i][j][r];
        s = (s > 0.0f ? s : 0.2f * s) * a;
        E[idx] = f2bf(__expf(s));
      }
    }
  }
}

// ---------------------------------------------------------------------------
// K4: per (b, 32-row e-tile). Double-buffered global_load_lds pipeline:
//   32 rounds (2 phases x 16 k-tiles of BK=32). Round t: barrier (drains
//   round-t DMA + round-(t-1) ds_reads) -> issue round-t+1 DMA -> compute
//   round t. Loads stay in flight across the whole compute phase.
//   phase0: H = E @ WhvT rows, + fused rowsum(E) via all-ones B fragment.
//   phase1: D = adj @ SupT rows.
// LDS linear, source pre-swizzled (chunk ^= (row>>1)&3): 2-way bank alias
// (free). 4 waves each own 64 output cols. LDS 37KB -> 3-4 blocks/CU.
// epilogue: h' = gate_g*H/rowsum ; LayerNorm ; dense = gate_d*D + sup + dgf_b;
//           out = 0.5*(dense+gat). Output dtype per flag.
// ---------------------------------------------------------------------------
__global__ __launch_bounds__(256, 3)
void k4_out(const u16* __restrict__ P, const u16* __restrict__ T,
            const u16* __restrict__ E, const u16* __restrict__ adj,
            const u16* __restrict__ G, const u16* __restrict__ PB,
            void* __restrict__ out, const u32* __restrict__ flag)
{
  __shared__ __align__(16) u16 ldsA[2][32 * 32];    // 2 x 2KB
  __shared__ __align__(16) u16 ldsB[2][256 * 32];   // 2 x 16KB
  __shared__ float red[32][8];
  const int et = blockIdx.x, b = blockIdx.y;
  const int e0 = et << 5;
  const int tid = threadIdx.x;
  const int wave = tid >> 6;
  const int wn = wave;              // wave owns output cols [wn*64, wn*64+64)
  const int lane = tid & 63;
  const int lr = lane & 15;
  const int kb = lane >> 4;

  const size_t abase = ((size_t)((b << 9) + e0)) << 9;
  const u16* Ea = E + abase;
  const u16* Aa = adj + abase;
  const u16* Tb = T + ((size_t)b << 18);
  const u16* WhvT = Tb + (256 << 9);
  const u16* SupT = Tb;

  // staging source offsets (u16 units, add lt*32 per round). LDS dest linear;
  // global source pre-swizzled so ds_read side lands conflict-lite.
  const int sAs = (wave << 6) + lane;          // A chunk id (waves 0,1 only)
  const int sAm = sAs >> 2;
  const int sAg = sAm * 512 + (((sAs & 3) ^ ((sAm >> 1) & 3)) << 3);
  int sBg[4];
#pragma unroll
  for (int q = 0; q < 4; ++q) {
    const int s = (((wave << 2) + q) << 6) + lane;   // B chunk id
    const int m = s >> 2;
    sBg[q] = m * 512 + (((s & 3) ^ ((m >> 1) & 3)) << 3);
  }

  // compute-side LDS fragment offsets (u16 units, loop-invariant)
  int offA[2], offB[4];
#pragma unroll
  for (int i = 0; i < 2; ++i) {
    const int m = (i << 4) + lr;
    offA[i] = ((m << 2) + (kb ^ ((m >> 1) & 3))) << 3;
  }
#pragma unroll
  for (int j = 0; j < 4; ++j) {
    const int n = (wn << 6) + (j << 4) + lr;
    offB[j] = ((n << 2) + (kb ^ ((n >> 1) & 3))) << 3;
  }

  f32x4 acc0[2][4], acc1[2][4], accS[2];
#pragma unroll
  for (int i = 0; i < 2; ++i) {
    accS[i] = f32x4{0.f, 0.f, 0.f, 0.f};
#pragma unroll
    for (int j = 0; j < 4; ++j) {
      acc0[i][j] = f32x4{0.f, 0.f, 0.f, 0.f};
      acc1[i][j] = f32x4{0.f, 0.f, 0.f, 0.f};
    }
  }
  const short onebf = (short)0x3F80;  // bf16 1.0
  const bf16x8 ones = {onebf, onebf, onebf, onebf, onebf, onebf, onebf, onebf};

  auto STAGE = [&](int t, int bi) {
    const int ko = (t & 15) << 5;
    const u16* Ag = (t >> 4) ? Aa : Ea;
    const u16* Bg = (t >> 4) ? SupT : WhvT;
    if (wave < 2)
      gld16(Ag + ko + sAg, &ldsA[bi][(size_t)(wave << 9)]);
#pragma unroll
    for (int q = 0; q < 4; ++q)
      gld16(Bg + ko + sBg[q], &ldsB[bi][(size_t)(((wave << 2) + q) << 9)]);
  };

  STAGE(0, 0);
#pragma unroll 1
  for (int t = 0; t < 32; ++t) {
    __syncthreads();                 // drains DMA for buf[t&1] + prior ds_reads
    if (t < 31) STAGE(t + 1, (t + 1) & 1);
    const int bi = t & 1;
    bf16x8 fa[2], fb[4];
#pragma unroll
    for (int i = 0; i < 2; ++i) fa[i] = *(const bf16x8*)&ldsA[bi][offA[i]];
#pragma unroll
    for (int j = 0; j < 4; ++j) fb[j] = *(const bf16x8*)&ldsB[bi][offB[j]];
    if (t < 16) {
#pragma unroll
      for (int i = 0; i < 2; ++i) {
#pragma unroll
        for (int j = 0; j < 4; ++j)
          acc0[i][j] = MFMA16(fa[i], fb[j], acc0[i][j]);
        accS[i] = MFMA16(fa[i], ones, accS[i]);   // rowsum(E) slice
      }
    } else {
#pragma unroll
      for (int i = 0; i < 2; ++i)
#pragma unroll
        for (int j = 0; j < 4; ++j)
          acc1[i][j] = MFMA16(fa[i], fb[j], acc1[i][j]);
    }
  }

  const u16* dgf_b = PB + 32768;
  const u16* ln_g  = PB + 33536;
  const u16* ln_b  = PB + 33792;
  const u32 isf32 = flag[0];

  float lng[4], lnb[4], dgb[4];
#pragma unroll
  for (int j = 0; j < 4; ++j) {
    const int col = (wn << 6) + (j << 4) + lr;
    lng[j] = bf2f(ln_g[col]);
    lnb[j] = bf2f(ln_b[col]);
    dgb[j] = bf2f(dgf_b[col]);
  }

  // phase-0 normalize (gate_g * H / rowsum) + per-wave LN partial sums
#pragma unroll
  for (int i = 0; i < 2; ++i) {
#pragma unroll
    for (int r = 0; r < 4; ++r) {
      const int rl = (i << 4) + ((lane >> 4) << 2) + r;
      const int grow = (b << 9) + e0 + rl;
      const float invS = 1.0f / accS[i][r];
      float ps = 0.0f, pq = 0.0f;
#pragma unroll
      for (int j = 0; j < 4; ++j) {
        const int col = (wn << 6) + (j << 4) + lr;
        const float gg = bf2f(G[((size_t)grow << 9) + 256 + col]);
        const float hp = gg * acc0[i][j][r] * invS;
        acc0[i][j][r] = hp;
        ps += hp; pq += hp * hp;
      }
#pragma unroll
      for (int m = 1; m < 16; m <<= 1) {
        ps += __shfl_xor(ps, m, 64);
        pq += __shfl_xor(pq, m, 64);
      }
      if (lr == 0) { red[rl][wn << 1] = ps; red[rl][(wn << 1) + 1] = pq; }
    }
  }
  __syncthreads();
#pragma unroll
  for (int i = 0; i < 2; ++i) {
#pragma unroll
    for (int r = 0; r < 4; ++r) {
      const int rl = (i << 4) + ((lane >> 4) << 2) + r;
      const int grow = (b << 9) + e0 + rl;
      const float mean = (red[rl][0] + red[rl][2] + red[rl][4] + red[rl][6]) * (1.0f / 256.0f);
      const float ex2  = (red[rl][1] + red[rl][3] + red[rl][5] + red[rl][7]) * (1.0f / 256.0f);
      const float rstd = rsqrtf(ex2 - mean * mean + 1e-5f);
#pragma unroll
      for (int j = 0; j < 4; ++j) {
        const int col = (wn << 6) + (j << 4) + lr;
        const float gat = (acc0[i][j][r] - mean) * rstd * lng[j] + lnb[j];
        const float gd = bf2f(G[((size_t)grow << 9) + col]);
        const float sup = bf2f(P[grow * 768 + col]);
        const float dense = gd * acc1[i][j][r] + sup + dgb[j];
        const float o = 0.5f * (dense + gat);
        if (isf32) ((float*)out)[grow * 256 + col] = o;
        else       ((u16*)out)[grow * 256 + col] = f2bf(o);
      }
    }
  }
}

// ---------------------------------------------------------------------------
extern "C" void kernel_launch(void* const* d_in, const int* in_sizes, int n_in,
                              void* d_out, int out_size, void* d_ws, size_t ws_size,
                              hipStream_t stream)
{
  (void)in_sizes; (void)n_in; (void)out_size; (void)ws_size;
  const void* inputs  = d_in[0];
  const void* adj     = d_in[1];
  const void* op_emb  = d_in[2];
  const void* dgf_W   = d_in[3];
  const void* dgf_b   = d_in[4];
  const void* dgf_opW = d_in[5];
  const void* dgf_opb = d_in[6];
  const void* Wk      = d_in[7];
  const void* Wv      = d_in[8];
  const void* Wq      = d_in[9];
  const void* a_w     = d_in[10];
  const void* gat_opW = d_in[11];
  const void* gat_opb = d_in[12];
  const void* ln_g    = d_in[13];
  const void* ln_b    = d_in[14];
  char* ws = (char*)d_ws;

  // workspace layout (bytes)
  u16*  P    = (u16*)(ws);                    // [32768,768]  50331648
  u16*  T    = (u16*)(ws + 50331648ull);      // [64,512,512] 33554432
  u16*  E    = (u16*)(ws + 83886080ull);      // [64,512,512] 33554432
  u16*  G    = (u16*)(ws + 117440512ull);     // [32768,512]  33554432
  u16*  Cadj = (u16*)(ws + 150994944ull);     // [64,512,512] 33554432
  u16*  Cin  = (u16*)(ws + 184549376ull);     // [32768,256]  16777216
  u16*  Cop  = (u16*)(ws + 201326592ull);     // [32768,64]    4194304
  u16*  Wcat = (u16*)(ws + 205520896ull);     // [1024,256]     524288
  u16*  PB   = (u16*)(ws + 206045184ull);     // params          69632
  u32*  flag = (u32*)(ws + 206245888ull);     // dtype flag        256

  kD_detect <<<dim3(1),       dim3(64),  0, stream>>>((const u16*)inputs, flag);
  kC_conv   <<<dim3(4096),    dim3(256), 0, stream>>>(inputs, Cin,  8388608, flag);
  kC_conv   <<<dim3(1024),    dim3(256), 0, stream>>>(op_emb, Cop,  2097152, flag);
  kC_conv   <<<dim3(8192),    dim3(256), 0, stream>>>(adj,    Cadj, 16777216, flag);
  kP_params <<<dim3(134),     dim3(256), 0, stream>>>(dgf_opW, gat_opW, dgf_b,
                                                      dgf_opb, gat_opb, ln_g, ln_b,
                                                      PB, flag);
  k0_wcat   <<<dim3(1024),    dim3(256), 0, stream>>>(dgf_W, Wk, Wv, Wq, a_w,
                                                      Wcat, flag);
  k1_proj   <<<dim3(256, 10), dim3(256), 0, stream>>>(Cin, Wcat, P, T);
  k2_gates  <<<dim3(256, 4),  dim3(256), 0, stream>>>(Cop, PB, G);
  k3_scores <<<dim3(4, 4, 64),dim3(256), 0, stream>>>(P, Cadj, E);
  k4_out    <<<dim3(16, 64),  dim3(256), 0, stream>>>(P, T, E, Cadj, G,
                                                      PB, d_out, flag);
}

// Round 3
// 323.493 us; speedup vs baseline: 1.1930x; 1.0433x over previous
//
#include <hip/hip_runtime.h>
#include <cstdint>
#include <cstddef>

typedef unsigned short u16;
typedef unsigned int   u32;
typedef __attribute__((ext_vector_type(8))) short bf16x8;
typedef __attribute__((ext_vector_type(4))) float f32x4;

#define MFMA16(a,b,c) __builtin_amdgcn_mfma_f32_16x16x32_bf16((a),(b),(c),0,0,0)

__device__ __forceinline__ float bf2f(u16 h){
  union { u32 u; float f; } v; v.u = ((u32)h) << 16; return v.f;
}
__device__ __forceinline__ u16 f2bf(float f){
  union { float f; u32 u; } v; v.f = f;
  u32 u = v.u + 0x7FFFu + ((v.u >> 16) & 1u);
  return (u16)(u >> 16);
}
// dual-dtype scalar read: flag!=0 -> source is f32, else packed bf16
__device__ __forceinline__ float ldf(const void* p, int i, u32 isf32){
  return isf32 ? ((const float*)p)[i] : bf2f(((const u16*)p)[i]);
}
// async global->LDS DMA, 16B per lane. LDS dest: wave-uniform base + lane*16.
__device__ __forceinline__ void gld16(const u16* g, u16* l){
  __builtin_amdgcn_global_load_lds(
      (const __attribute__((address_space(1))) void*)g,
      (__attribute__((address_space(3))) void*)l, 16, 0, 0);
}

// ---------------------------------------------------------------------------
// kD: dtype probe. Read first 64 u16 of `inputs` as bf16; true bf16 N(0,1)
// stays |v|<10, f32-mantissa halves blow past 1e6 w.p. ~1-1e-8.
// ---------------------------------------------------------------------------
__global__ void kD_detect(const u16* __restrict__ raw, u32* __restrict__ flag)
{
  const int lane = threadIdx.x & 63;
  const float v = bf2f(raw[lane]);
  const unsigned long long big = __ballot(fabsf(v) > 1.0e6f);
  if (lane == 0) flag[0] = (big != 0ull) ? 1u : 0u;
}

// ---------------------------------------------------------------------------
// kC: canonicalize a tensor to bf16 (convert from f32, or bit-copy bf16).
// n multiple of 8.
// ---------------------------------------------------------------------------
__global__ void kC_conv(const void* __restrict__ src, u16* __restrict__ dst,
                        int n, const u32* __restrict__ flag)
{
  const int i8 = (blockIdx.x * 256 + threadIdx.x) << 3;
  if (i8 >= n) return;
  if (flag[0]) {
    const float4 a = ((const float4*)src)[i8 >> 2];
    const float4 b = ((const float4*)src)[(i8 >> 2) + 1];
    u16 o[8] = { f2bf(a.x), f2bf(a.y), f2bf(a.z), f2bf(a.w),
                 f2bf(b.x), f2bf(b.y), f2bf(b.z), f2bf(b.w) };
    *(uint4*)&dst[i8] = *(const uint4*)o;
  } else {
    ((uint4*)dst)[i8 >> 3] = ((const uint4*)src)[i8 >> 3];
  }
}

// ---------------------------------------------------------------------------
// kP: param block PB (u16), dual-path reads:
// [0,16384) dgf_opW | [16384,32768) gat_opW | [32768,33024) dgf_b
// [33024,33280) dgf_opb | [33280,33536) gat_opb | [33536,33792) ln_g
// [33792,34048) ln_b
// ---------------------------------------------------------------------------
__global__ void kP_params(const void* dgf_opW, const void* gat_opW,
                          const void* dgf_b,   const void* dgf_opb,
                          const void* gat_opb, const void* ln_g,
                          const void* ln_b,    u16* __restrict__ PB,
                          const u32* __restrict__ flag)
{
  const int i = blockIdx.x * 256 + threadIdx.x;
  if (i >= 34048) return;
  const u32 f = flag[0];
  float v;
  if      (i < 16384) v = ldf(dgf_opW, i, f);
  else if (i < 32768) v = ldf(gat_opW, i - 16384, f);
  else if (i < 33024) v = ldf(dgf_b,   i - 32768, f);
  else if (i < 33280) v = ldf(dgf_opb, i - 33024, f);
  else if (i < 33536) v = ldf(gat_opb, i - 33280, f);
  else if (i < 33792) v = ldf(ln_g,    i - 33536, f);
  else                v = ldf(ln_b,    i - 33792, f);
  PB[i] = f2bf(v);
}

// ---------------------------------------------------------------------------
// K0: WcatT [1024,256] bf16, dual-path reads:
//   rows   0-255 : dgf_W[i][o] (transpose)   rows 256-511 : Wk[o][i]
//   rows 512-767 : Wv[o][i]                  rows 768-1023: Wq[o][i]*a_w[o]/16
// ---------------------------------------------------------------------------
__global__ void k0_wcat(const void* dgfW, const void* Wk, const void* Wv,
                        const void* Wq, const void* aw, u16* __restrict__ Wcat,
                        const u32* __restrict__ flag)
{
  const int o = blockIdx.x;
  const int i = threadIdx.x;
  const u32 f = flag[0];
  float v;
  if (o < 256)       v = ldf(dgfW, i * 256 + o, f);
  else if (o < 512)  v = ldf(Wk, (o - 256) * 256 + i, f);
  else if (o < 768)  v = ldf(Wv, (o - 512) * 256 + i, f);
  else               v = ldf(Wq, (o - 768) * 256 + i, f) * ldf(aw, o - 768, f) * 0.0625f;
  Wcat[o * 256 + i] = f2bf(v);
}

// ---------------------------------------------------------------------------
// K1: X[32768,256] @ WcatT^T, 128x128 tiles, BK=64, XOR-swizzled LDS.
// Staging via global_load_lds w=16: LDS linear, source pre-swizzled (rule 21).
// ct 0-3: support/Whk -> P ; 6,7: Whq_pre -> P
// ct 4,5: Whv -> T rows 256-511 (swapped => C^T) ; 8,9: support -> T rows 0-255
// P [32768,768]: 0-255 support, 256-511 Whk, 512-767 Whq_pre.
// T [64][512][512]: rows 0-255 supportT, 256-511 WhvT.
// ---------------------------------------------------------------------------
__global__ __launch_bounds__(256, 2)
void k1_proj(const u16* __restrict__ X, const u16* __restrict__ W,
             u16* __restrict__ P, u16* __restrict__ T)
{
  __shared__ __align__(16) u16 ldsA[128 * 64];
  __shared__ __align__(16) u16 ldsB[128 * 64];
  const int bt = blockIdx.x;
  const int ct = blockIdx.y;
  const int r0 = bt << 7;
  const bool swapped = (ct == 4) | (ct == 5) | (ct >= 8);
  const int wbase = (ct < 8) ? (ct << 7) : ((ct - 8) << 7);
  const int tid = threadIdx.x;
  const int wave = tid >> 6;
  const int lane = tid & 63;
  const int wm = wave >> 1, wn = wave & 1;

  // staging: per-thread source offsets (pre-swizzled), LDS dest linear
  int gA[4], gB[4], dS[4];
#pragma unroll
  for (int s = 0; s < 4; ++s) {
    const int slot = ((wave * 4 + s) << 6) + lane;
    const int m = slot >> 3, c = slot & 7;
    const int kb = c ^ (m & 7);
    gA[s] = (r0 + m) * 256 + (kb << 3);
    gB[s] = (wbase + m) * 256 + (kb << 3);
    dS[s] = slot << 3;
  }

  f32x4 acc[4][4];
#pragma unroll
  for (int i = 0; i < 4; ++i)
#pragma unroll
    for (int j = 0; j < 4; ++j) acc[i][j] = f32x4{0.f, 0.f, 0.f, 0.f};

  for (int kt = 0; kt < 4; ++kt) {
    __syncthreads();
#pragma unroll
    for (int s = 0; s < 4; ++s) {
      gld16(X + gA[s] + (kt << 6), &ldsA[dS[s]]);
      gld16(W + gB[s] + (kt << 6), &ldsB[dS[s]]);
    }
    __syncthreads();
#pragma unroll
    for (int ks = 0; ks < 2; ++ks) {
      const int kb = (ks << 2) + (lane >> 4);
      bf16x8 fa[4], fb[4];
#pragma unroll
      for (int i = 0; i < 4; ++i) {
        const int m = (wm << 6) + (i << 4) + (lane & 15);
        fa[i] = *(const bf16x8*)&ldsA[((m << 3) + (kb ^ (m & 7))) << 3];
        const int n = (wn << 6) + (i << 4) + (lane & 15);
        fb[i] = *(const bf16x8*)&ldsB[((n << 3) + (kb ^ (n & 7))) << 3];
      }
      if (!swapped) {
#pragma unroll
        for (int i = 0; i < 4; ++i)
#pragma unroll
          for (int j = 0; j < 4; ++j)
            acc[i][j] = MFMA16(fa[i], fb[j], acc[i][j]);
      } else {
#pragma unroll
        for (int i = 0; i < 4; ++i)
#pragma unroll
          for (int j = 0; j < 4; ++j)
            acc[i][j] = MFMA16(fb[i], fa[j], acc[i][j]);
      }
    }
  }

  if (!swapped) {
    const int pcb = (ct < 4) ? (ct << 7) : ((ct - 2) << 7);
#pragma unroll
    for (int i = 0; i < 4; ++i) {
      const int row = r0 + (wm << 6) + (i << 4) + ((lane >> 4) << 2);
#pragma unroll
      for (int j = 0; j < 4; ++j) {
        const int col = pcb + (wn << 6) + (j << 4) + (lane & 15);
#pragma unroll
        for (int r = 0; r < 4; ++r)
          P[(row + r) * 768 + col] = f2bf(acc[i][j][r]);
      }
    }
  } else {
    // acc[i][j] = MFMA(fb[i], fa[j]): C rows carry wn offset, C cols carry wm.
    const int trb = (wbase >= 512) ? (wbase - 256) : wbase;
    const int b = r0 >> 9;
    const int e0 = r0 & 511;
    u16* Tb = T + ((size_t)b << 18);
#pragma unroll
    for (int i = 0; i < 4; ++i) {
      const int trow = trb + (wn << 6) + (i << 4) + ((lane >> 4) << 2);
#pragma unroll
      for (int j = 0; j < 4; ++j) {
        const int e = e0 + (wm << 6) + (j << 4) + (lane & 15);
#pragma unroll
        for (int r = 0; r < 4; ++r)
          Tb[((trow + r) << 9) + e] = f2bf(acc[i][j][r]);
      }
    }
  }
}

// ---------------------------------------------------------------------------
// K2: gates = sigmoid(op_emb[32768,64] @ opW^T + b) -> G[32768,512] bf16
// cols 0-255 gate_d, 256-511 gate_g. Weights/biases from PB.
// ---------------------------------------------------------------------------
__global__ __launch_bounds__(256, 2)
void k2_gates(const u16* __restrict__ OP, const u16* __restrict__ PB,
              u16* __restrict__ G)
{
  __shared__ __align__(16) u16 ldsA[128 * 64];
  __shared__ __align__(16) u16 ldsB[128 * 64];
  const int bt = blockIdx.x, ct = blockIdx.y;
  const int r0 = bt << 7;
  const u16* Wp = (ct < 2) ? (PB + (ct << 7) * 64) : (PB + 16384 + ((ct - 2) << 7) * 64);
  const u16* Bp = (ct < 2) ? (PB + 33024 + (ct << 7)) : (PB + 33280 + ((ct - 2) << 7));
  const int tid = threadIdx.x, wave = tid >> 6, lane = tid & 63;
  const int wm = wave >> 1, wn = wave & 1;

  f32x4 acc[4][4];
#pragma unroll
  for (int i = 0; i < 4; ++i)
#pragma unroll
    for (int j = 0; j < 4; ++j) acc[i][j] = f32x4{0.f, 0.f, 0.f, 0.f};

#pragma unroll
  for (int s = 0; s < 4; ++s) {
    const int slot = ((wave * 4 + s) << 6) + lane;
    const int m = slot >> 3, c = slot & 7;
    const int kb = c ^ (m & 7);
    *(uint4*)&ldsA[slot << 3] = *(const uint4*)(OP + (r0 + m) * 64 + (kb << 3));
    *(uint4*)&ldsB[slot << 3] = *(const uint4*)(Wp + m * 64 + (kb << 3));
  }
  __syncthreads();
#pragma unroll
  for (int ks = 0; ks < 2; ++ks) {
    const int kb = (ks << 2) + (lane >> 4);
    bf16x8 fa[4], fb[4];
#pragma unroll
    for (int i = 0; i < 4; ++i) {
      const int m = (wm << 6) + (i << 4) + (lane & 15);
      fa[i] = *(const bf16x8*)&ldsA[((m << 3) + (kb ^ (m & 7))) << 3];
      const int n = (wn << 6) + (i << 4) + (lane & 15);
      fb[i] = *(const bf16x8*)&ldsB[((n << 3) + (kb ^ (n & 7))) << 3];
    }
#pragma unroll
    for (int i = 0; i < 4; ++i)
#pragma unroll
      for (int j = 0; j < 4; ++j)
        acc[i][j] = MFMA16(fa[i], fb[j], acc[i][j]);
  }
#pragma unroll
  for (int i = 0; i < 4; ++i) {
    const int row = r0 + (wm << 6) + (i << 4) + ((lane >> 4) << 2);
#pragma unroll
    for (int j = 0; j < 4; ++j) {
      const int cw = (wn << 6) + (j << 4) + (lane & 15);
      const float bias = bf2f(Bp[cw]);
      const int col = (ct << 7) + cw;
#pragma unroll
      for (int r = 0; r < 4; ++r) {
        const float x = acc[i][j][r] + bias;
        G[((row + r) << 9) + col] = f2bf(1.0f / (1.0f + __expf(-x)));
      }
    }
  }
}

// ---------------------------------------------------------------------------
// K3: per-batch scores S = Whq_pre @ Whk^T; E = exp(leaky(S)*adj) bf16.
// Staging via global_load_lds w=16 (same pattern as K1).
// No max-subtraction: |alpha| < ~0.2 by construction.
// ---------------------------------------------------------------------------
__global__ __launch_bounds__(256, 2)
void k3_scores(const u16* __restrict__ P, const u16* __restrict__ adj,
               u16* __restrict__ E)
{
  __shared__ __align__(16) u16 ldsA[128 * 64];
  __shared__ __align__(16) u16 ldsB[128 * 64];
  const int lt = blockIdx.x, et = blockIdx.y, b = blockIdx.z;
  const int e0 = et << 7, l0 = lt << 7;
  const int tid = threadIdx.x, wave = tid >> 6, lane = tid & 63;
  const int wm = wave >> 1, wn = wave & 1;
  const int rowQ = (b << 9) + e0;
  const int rowK = (b << 9) + l0;

  int gA[4], gB[4], dS[4];
#pragma unroll
  for (int s = 0; s < 4; ++s) {
    const int slot = ((wave * 4 + s) << 6) + lane;
    const int m = slot >> 3, c = slot & 7;
    const int kb = c ^ (m & 7);
    gA[s] = (rowQ + m) * 768 + 512 + (kb << 3);
    gB[s] = (rowK + m) * 768 + 256 + (kb << 3);
    dS[s] = slot << 3;
  }

  f32x4 acc[4][4];
#pragma unroll
  for (int i = 0; i < 4; ++i)
#pragma unroll
    for (int j = 0; j < 4; ++j) acc[i][j] = f32x4{0.f, 0.f, 0.f, 0.f};

  for (int kt = 0; kt < 4; ++kt) {
    __syncthreads();
#pragma unroll
    for (int s = 0; s < 4; ++s) {
      gld16(P + gA[s] + (kt << 6), &ldsA[dS[s]]);
      gld16(P + gB[s] + (kt << 6), &ldsB[dS[s]]);
    }
    __syncthreads();
#pragma unroll
    for (int ks = 0; ks < 2; ++ks) {
      const int kb = (ks << 2) + (lane >> 4);
      bf16x8 fa[4], fb[4];
#pragma unroll
      for (int i = 0; i < 4; ++i) {
        const int m = (wm << 6) + (i << 4) + (lane & 15);
        fa[i] = *(const bf16x8*)&ldsA[((m << 3) + (kb ^ (m & 7))) << 3];
        const int n = (wn << 6) + (i << 4) + (lane & 15);
        fb[i] = *(const bf16x8*)&ldsB[((n << 3) + (kb ^ (n & 7))) << 3];
      }
#pragma unroll
      for (int i = 0; i < 4; ++i)
#pragma unroll
        for (int j = 0; j < 4; ++j)
          acc[i][j] = MFMA16(fa[i], fb[j], acc[i][j]);
    }
  }
#pragma unroll
  for (int i = 0; i < 4; ++i) {
    const int e = e0 + (wm << 6) + (i << 4) + ((lane >> 4) << 2);
#pragma unroll
    for (int j = 0; j < 4; ++j) {
      const int l = l0 + (wn << 6) + (j << 4) + (lane & 15);
#pragma unroll
      for (int r = 0; r < 4; ++r) {
        const int idx = (((b << 9) + e + r) << 9) + l;
        const float a = bf2f(adj[idx]);
        float s = acc[i][j][r];
        s = (s > 0.0f ? s : 0.2f * s) * a;
        E[idx] = f2bf(__expf(s));
      }
    }
  }
}

// ---------------------------------------------------------------------------
// K4: per (b, 64-row e-tile), big rounds (BK=64), gld16 single-buffered:
//   phase0: H = E @ Whv (via WhvT rows of T), + fused rowsum(E) via all-ones
//           B fragment (replaces old k3b kernel).
//   phase1: D = adj @ support (via supportT rows of T).
// 16 rounds (2 ph x 8 lt), 40KB staged/round via global_load_lds w=16
// (1 instr/16B, no VGPR round-trip), 2 barriers/round (m97 structure).
// epilogue: h' = gate_g*H/rowsum ; LayerNorm ; dense = gate_d*D + sup + dgf_b;
//           out = 0.5*(dense+gat). Output dtype per flag.
// ---------------------------------------------------------------------------
__global__ __launch_bounds__(256, 2)
void k4_out(const u16* __restrict__ P, const u16* __restrict__ T,
            const u16* __restrict__ E, const u16* __restrict__ adj,
            const u16* __restrict__ G, const u16* __restrict__ PB,
            void* __restrict__ out, const u32* __restrict__ flag)
{
  __shared__ __align__(16) u16 ldsA[64 * 64];
  __shared__ __align__(16) u16 ldsB[256 * 64];
  __shared__ float red[64][4];
  const int et = blockIdx.x, b = blockIdx.y;
  const int e0 = et << 6;
  const int tid = threadIdx.x, wave = tid >> 6, lane = tid & 63;
  const int wm = wave >> 1, wn = wave & 1;
  const size_t abase = ((size_t)((b << 9) + e0)) << 9;
  const u16* Ea  = E + abase;
  const u16* Aa  = adj + abase;
  const u16* Tb  = T + ((size_t)b << 18);
  const u16* WhvT = Tb + (256 << 9);
  const u16* SupT = Tb;
  const u16* dgf_b = PB + 32768;
  const u16* ln_g  = PB + 33536;
  const u16* ln_b  = PB + 33792;
  const u32 isf32 = flag[0];

  // staging source offsets (pre-swizzled, sans lt term) + linear LDS dests
  int gA[2], dA[2], gB[8], dB[8];
#pragma unroll
  for (int s2 = 0; s2 < 2; ++s2) {
    const int slot = ((wave * 2 + s2) << 6) + lane;
    const int m = slot >> 3, c = slot & 7;
    gA[s2] = (m << 9) + ((c ^ (m & 7)) << 3);
    dA[s2] = slot << 3;
  }
#pragma unroll
  for (int s2 = 0; s2 < 8; ++s2) {
    const int slot = ((wave * 8 + s2) << 6) + lane;
    const int m = slot >> 3, c = slot & 7;
    gB[s2] = (m << 9) + ((c ^ (m & 7)) << 3);
    dB[s2] = slot << 3;
  }

  f32x4 acc[2][2][8], accS[2];
#pragma unroll
  for (int i = 0; i < 2; ++i) {
    accS[i] = f32x4{0.f, 0.f, 0.f, 0.f};
#pragma unroll
    for (int p = 0; p < 2; ++p)
#pragma unroll
      for (int j = 0; j < 8; ++j) acc[p][i][j] = f32x4{0.f, 0.f, 0.f, 0.f};
  }
  const short onebf = (short)0x3F80;  // bf16 1.0
  const bf16x8 ones = {onebf, onebf, onebf, onebf, onebf, onebf, onebf, onebf};

#pragma unroll
  for (int ph = 0; ph < 2; ++ph) {
    const u16* Ag = ph ? Aa : Ea;
    const u16* Bg = ph ? SupT : WhvT;
    for (int lt = 0; lt < 8; ++lt) {
      __syncthreads();
#pragma unroll
      for (int s2 = 0; s2 < 2; ++s2)
        gld16(Ag + gA[s2] + (lt << 6), &ldsA[dA[s2]]);
#pragma unroll
      for (int s2 = 0; s2 < 8; ++s2)
        gld16(Bg + gB[s2] + (lt << 6), &ldsB[dB[s2]]);
      __syncthreads();
#pragma unroll
      for (int ks = 0; ks < 2; ++ks) {
        const int kb = (ks << 2) + (lane >> 4);
        bf16x8 fa[2];
#pragma unroll
        for (int i = 0; i < 2; ++i) {
          const int m = (wm << 5) + (i << 4) + (lane & 15);
          fa[i] = *(const bf16x8*)&ldsA[((m << 3) + (kb ^ (m & 7))) << 3];
        }
#pragma unroll
        for (int j = 0; j < 8; ++j) {
          const int n = (wn << 7) + (j << 4) + (lane & 15);
          const bf16x8 fb = *(const bf16x8*)&ldsB[((n << 3) + (kb ^ (n & 7))) << 3];
          acc[ph][0][j] = MFMA16(fa[0], fb, acc[ph][0][j]);
          acc[ph][1][j] = MFMA16(fa[1], fb, acc[ph][1][j]);
        }
        if (ph == 0) {
          accS[0] = MFMA16(fa[0], ones, accS[0]);   // rowsum(E) slices
          accS[1] = MFMA16(fa[1], ones, accS[1]);
        }
      }
    }
  }

  const int cb = wn << 7;
  float lng[8], lnb[8], dgb[8];
#pragma unroll
  for (int j = 0; j < 8; ++j) {
    const int col = cb + (j << 4) + (lane & 15);
    lng[j] = bf2f(ln_g[col]);
    lnb[j] = bf2f(ln_b[col]);
    dgb[j] = bf2f(dgf_b[col]);
  }
#pragma unroll
  for (int i = 0; i < 2; ++i) {
#pragma unroll
    for (int r = 0; r < 4; ++r) {
      const int rl = (wm << 5) + (i << 4) + ((lane >> 4) << 2) + r;
      const int grow = (b << 9) + e0 + rl;
      const float invS = 1.0f / accS[i][r];
      float ps = 0.0f, pq = 0.0f;
#pragma unroll
      for (int j = 0; j < 8; ++j) {
        const int col = cb + (j << 4) + (lane & 15);
        const float gg = bf2f(G[((size_t)grow << 9) + 256 + col]);
        const float hp = gg * acc[0][i][j][r] * invS;
        acc[0][i][j][r] = hp;
        ps += hp; pq += hp * hp;
      }
#pragma unroll
      for (int m = 1; m < 16; m <<= 1) {
        ps += __shfl_xor(ps, m, 64);
        pq += __shfl_xor(pq, m, 64);
      }
      if ((lane & 15) == 0) { red[rl][wn << 1] = ps; red[rl][(wn << 1) + 1] = pq; }
    }
  }
  __syncthreads();
#pragma unroll
  for (int i = 0; i < 2; ++i) {
#pragma unroll
    for (int r = 0; r < 4; ++r) {
      const int rl = (wm << 5) + (i << 4) + ((lane >> 4) << 2) + r;
      const int grow = (b << 9) + e0 + rl;
      const float mean = (red[rl][0] + red[rl][2]) * (1.0f / 256.0f);
      const float ex2  = (red[rl][1] + red[rl][3]) * (1.0f / 256.0f);
      const float rstd = rsqrtf(ex2 - mean * mean + 1e-5f);
#pragma unroll
      for (int j = 0; j < 8; ++j) {
        const int col = cb + (j << 4) + (lane & 15);
        const float gat = (acc[0][i][j][r] - mean) * rstd * lng[j] + lnb[j];
        const float gd = bf2f(G[((size_t)grow << 9) + col]);
        const float sup = bf2f(P[grow * 768 + col]);
        const float dense = gd * acc[1][i][j][r] + sup + dgb[j];
        const float o = 0.5f * (dense + gat);
        if (isf32) ((float*)out)[grow * 256 + col] = o;
        else       ((u16*)out)[grow * 256 + col] = f2bf(o);
      }
    }
  }
}

// ---------------------------------------------------------------------------
extern "C" void kernel_launch(void* const* d_in, const int* in_sizes, int n_in,
                              void* d_out, int out_size, void* d_ws, size_t ws_size,
                              hipStream_t stream)
{
  (void)in_sizes; (void)n_in; (void)out_size; (void)ws_size;
  const void* inputs  = d_in[0];
  const void* adj     = d_in[1];
  const void* op_emb  = d_in[2];
  const void* dgf_W   = d_in[3];
  const void* dgf_b   = d_in[4];
  const void* dgf_opW = d_in[5];
  const void* dgf_opb = d_in[6];
  const void* Wk      = d_in[7];
  const void* Wv      = d_in[8];
  const void* Wq      = d_in[9];
  const void* a_w     = d_in[10];
  const void* gat_opW = d_in[11];
  const void* gat_opb = d_in[12];
  const void* ln_g    = d_in[13];
  const void* ln_b    = d_in[14];
  char* ws = (char*)d_ws;

  // workspace layout (bytes)
  u16*  P    = (u16*)(ws);                    // [32768,768]  50331648
  u16*  T    = (u16*)(ws + 50331648ull);      // [64,512,512] 33554432
  u16*  E    = (u16*)(ws + 83886080ull);      // [64,512,512] 33554432
  u16*  G    = (u16*)(ws + 117440512ull);     // [32768,512]  33554432
  u16*  Cadj = (u16*)(ws + 150994944ull);     // [64,512,512] 33554432
  u16*  Cin  = (u16*)(ws + 184549376ull);     // [32768,256]  16777216
  u16*  Cop  = (u16*)(ws + 201326592ull);     // [32768,64]    4194304
  u16*  Wcat = (u16*)(ws + 205520896ull);     // [1024,256]     524288
  u16*  PB   = (u16*)(ws + 206045184ull);     // params          69632
  u32*  flag = (u32*)(ws + 206245888ull);     // dtype flag        256

  kD_detect <<<dim3(1),       dim3(64),  0, stream>>>((const u16*)inputs, flag);
  kC_conv   <<<dim3(4096),    dim3(256), 0, stream>>>(inputs, Cin,  8388608, flag);
  kC_conv   <<<dim3(1024),    dim3(256), 0, stream>>>(op_emb, Cop,  2097152, flag);
  kC_conv   <<<dim3(8192),    dim3(256), 0, stream>>>(adj,    Cadj, 16777216, flag);
  kP_params <<<dim3(134),     dim3(256), 0, stream>>>(dgf_opW, gat_opW, dgf_b,
                                                      dgf_opb, gat_opb, ln_g, ln_b,
                                                      PB, flag);
  k0_wcat   <<<dim3(1024),    dim3(256), 0, stream>>>(dgf_W, Wk, Wv, Wq, a_w,
                                                      Wcat, flag);
  k1_proj   <<<dim3(256, 10), dim3(256), 0, stream>>>(Cin, Wcat, P, T);
  k2_gates  <<<dim3(256, 4),  dim3(256), 0, stream>>>(Cop, PB, G);
  k3_scores <<<dim3(4, 4, 64),dim3(256), 0, stream>>>(P, Cadj, E);
  k4_out    <<<dim3(8, 64),   dim3(256), 0, stream>>>(P, T, E, Cadj, G,
                                                      PB, d_out, flag);
}